// Round 17
// baseline (150.927 us; speedup 1.0000x reference)
//
#include <hip/hip_runtime.h>

typedef float f4 __attribute__((ext_vector_type(4)));

static constexpr int Hh = 256, Ww = 256, HW = Hh * Ww;
static constexpr int PLANES = 512;            // N*C
static constexpr int STRIPS = 4;
static constexpr int ROWS   = Hh / STRIPS;    // 64
static constexpr int DEPTH  = 10;
static constexpr int RB     = 4;              // rows advanced per sweep step
static constexpr int NSTEP  = (ROWS + 2 * DEPTH) / RB;   // 21

#if __has_builtin(__builtin_amdgcn_exp2f)
#define EXP2F(x) __builtin_amdgcn_exp2f(x)
#else
#define EXP2F(x) __expf((x) * 0.6931471805599453f)
#endif

static constexpr float LN2 = 0.6931471805599453f;
static constexpr float L2E = 1.4426950408889634f;
static constexpr float AZS = 10.0f * L2E;     // Z = AZS * z  (BETA+log2e folded)

// deg-2 minimax of ln(1+p), p = 2^(-|Z|); max(Z,0) folded into coefficients
// (error budget: absmax saturated at 2.0 across rounds; threshold 10.04)
static constexpr float A1c = 0.9897f;
static constexpr float A2c = -0.3059f;
static constexpr float TA = -0.12f * LN2;
static constexpr float TB = -0.08f * LN2;
static constexpr float TCA1 = -0.16f * A1c;
static constexpr float TCA2 = -0.16f * A2c;
static constexpr float UA = 0.06f * LN2;
static constexpr float UB = 0.04f * LN2;
static constexpr float UCA1 = 0.08f * A1c;
static constexpr float UCA2 = 0.08f * A2c;

// 6 ops: az, exp2, 4 fma
__device__ __forceinline__ float tval_s(float Z) {
    float az = fabsf(Z);
    float p  = EXP2F(-az);                    // neg folds into src modifier
    float r  = fmaf(TCA2, p, TCA1);
    float s  = fmaf(r, p, 1.0f);              // 1 + TC*ln(1+p)
    return fmaf(TA, Z, fmaf(TB, az, s));
}
// 6 ops
__device__ __forceinline__ float uval_s(float Z) {
    float az = fabsf(Z);
    float p  = EXP2F(-az);
    float r  = fmaf(UCA2, p, UCA1);
    float su = r * p;                         // UC*ln(1+p)
    return fmaf(UA, Z, fmaf(UB, az, su));
}

// ---- per-row stage components (expanded inside STEP_BODY; B = border flag) --
// horizontal conv of row m, consuming lfc/rgc (issued one stage earlier)
#define HN_M(m)                                                              \
    hn[m][0] = fmaf(w1s, tin[m][0], fmaf(w0s, tin[m][1], w0L * lfc[m]));     \
    hn[m][1] = fmaf(w1s, tin[m][1], w0s * (tin[m][0] + tin[m][2]));          \
    hn[m][2] = fmaf(w1s, tin[m][2], w0s * (tin[m][1] + tin[m][3]));          \
    hn[m][3] = fmaf(w1s, tin[m][3], fmaf(w0s, tin[m][2], w0R * rgc[m]));

// vertical conv + activation for row m (overwrites tin[m])
#define EV_M(m, B)                                                           \
    { const bool rv = !B || (unsigned)(yS - k + m) < 256u;                   \
      _Pragma("unroll") for (int i = 0; i < 4; ++i) {                        \
        float h_im1 = (m == 0) ? hA[k-1][i] : (m == 1) ? hB[k-1][i] : hn[m-2][i]; \
        float h_i   = (m == 0) ? hB[k-1][i] : hn[m-1][i];                    \
        float Z = fmaf(W0Z, h_im1 + hn[m][i],                                \
                  fmaf(W1Z, h_i, og[DEPTH - k + m][i]));                     \
        if (k < DEPTH) { float tv = tval_s(Z); tin[m][i] = rv ? tv : 0.f; }  \
        else           { tin[m][i] = uval_s(Z); }                            \
      } }

// issue row m's bpermutes for the NEXT stage the moment tin[m] is final:
// they fly during the remaining rows' eval work (~300 cyc) instead of
// stalling stage k+1's HFMA (the ~290 cyc/stage idle measured R11-R16).
#define PB_M(m)                                                              \
    if (k < DEPTH) {                                                         \
        lfn[m] = __int_as_float(__builtin_amdgcn_ds_bpermute(a_up, __float_as_int(tin[m][3]))); \
        rgn[m] = __int_as_float(__builtin_amdgcn_ds_bpermute(a_dn, __float_as_int(tin[m][0]))); \
    }

// One sweep step. BORDER is a literal; pnext[4][4] carries the next step's
// stage-0 rows (prefetched one full step ahead -> no vmcnt stall at stage 0).
#define STEP_BODY(BORDER) do {                                               \
    float og[DEPTH + RB][4];                                                 \
    float lfc[RB], rgc[RB], lfn[RB], rgn[RB];                                \
    /* stage-0 rows: consume prefetch (long since returned), scale to Z */   \
    _Pragma("unroll")                                                        \
    for (int m = 0; m < RB; ++m)                                             \
        { _Pragma("unroll") for (int i = 0; i < 4; ++i) og[DEPTH + m][i] = AZS * pnext[m][i]; } \
    /* issue current-step rows og[9]..og[0] in consumption order (raw) */    \
    _Pragma("unroll")                                                        \
    for (int t = DEPTH - 1; t >= 0; --t) {                                   \
        int r = yS - DEPTH + t;                                              \
        if (BORDER) r = r < 0 ? 0 : (r > 255 ? 255 : r);                     \
        f4 v = *reinterpret_cast<const f4*>(op_lane + r * Ww);               \
        og[t][0] = v.x; og[t][1] = v.y; og[t][2] = v.z; og[t][3] = v.w;      \
    }                                                                        \
    /* issue NEXT step's stage-0 prefetch (rows yS+4..yS+7, always clamped) */\
    _Pragma("unroll")                                                        \
    for (int m = 0; m < RB; ++m) {                                           \
        int r = yS + RB + m;                                                 \
        r = r < 0 ? 0 : (r > 255 ? 255 : r);                                 \
        f4 v = *reinterpret_cast<const f4*>(op_lane + r * Ww);               \
        pnext[m][0] = v.x; pnext[m][1] = v.y; pnext[m][2] = v.z; pnext[m][3] = v.w; \
    }                                                                        \
    asm volatile("" ::: "memory");               /* pin loads above compute */\
    float tin[RB][4];                                                        \
    /* stage 0: per-row eval, bpermutes issued immediately after each row */ \
    _Pragma("unroll")                                                        \
    for (int m = 0; m < RB; ++m) {                                           \
        const bool rv = !BORDER || (unsigned)(yS + m) < 256u;                \
        _Pragma("unroll")                                                    \
        for (int i = 0; i < 4; ++i) {                                        \
            float tv = tval_s(og[DEPTH + m][i]);                             \
            tin[m][i] = rv ? tv : 0.f;                                       \
        }                                                                    \
        lfc[m] = __int_as_float(__builtin_amdgcn_ds_bpermute(a_up, __float_as_int(tin[m][3]))); \
        rgc[m] = __int_as_float(__builtin_amdgcn_ds_bpermute(a_dn, __float_as_int(tin[m][0]))); \
    }                                                                        \
    /* scale current rows to Z-domain (loads now have ~stage-0 of cover) */  \
    _Pragma("unroll")                                                        \
    for (int t = 0; t < DEPTH; ++t)                                          \
        { _Pragma("unroll") for (int i = 0; i < 4; ++i) og[t][i] *= AZS; }   \
    _Pragma("unroll")                                                        \
    for (int k = 1; k <= DEPTH; ++k) {                                       \
        float hn[RB][4];                                                     \
        HN_M(0) HN_M(1)                                                      \
        EV_M(0, BORDER) PB_M(0)                                              \
        HN_M(2)                                                              \
        EV_M(1, BORDER) PB_M(1)                                              \
        HN_M(3)                                                              \
        EV_M(2, BORDER) PB_M(2)                                              \
        EV_M(3, BORDER) PB_M(3)                                              \
        _Pragma("unroll")                                                    \
        for (int i = 0; i < 4; ++i) { hA[k - 1][i] = hn[2][i]; hB[k - 1][i] = hn[3][i]; } \
        if (k < DEPTH) {                                                     \
            _Pragma("unroll")                                                \
            for (int m = 0; m < RB; ++m) { lfc[m] = lfn[m]; rgc[m] = rgn[m]; } \
        }                                                                    \
    }                                                                        \
    _Pragma("unroll")                                                        \
    for (int m = 0; m < RB; ++m) {                                           \
        const int r = yS - DEPTH + m;                                        \
        if (r >= y0 && r < y0 + ROWS) {                                      \
            f4 v; v.x = tin[m][0]; v.y = tin[m][1]; v.z = tin[m][2]; v.w = tin[m][3]; \
            *reinterpret_cast<f4*>(up_lane + r * Ww) = v;                    \
        }                                                                    \
    }                                                                        \
} while (0)

// R11 geometry (2048 waves = 2/SIMD, VGPR~100, zero scratch) + R16's
// de-phase sleep (harmless) + in-chain bpermute pipelining (this round).
__global__ __launch_bounds__(64)
__attribute__((amdgpu_waves_per_eu(2, 2)))
void k_fused(const float* __restrict__ o, const float* __restrict__ sigma,
             const float* __restrict__ lam, float* __restrict__ out) {
    const int lane  = threadIdx.x;
    const int bid   = blockIdx.x;

    if (bid >= (PLANES * STRIPS) / 2) {
        __builtin_amdgcn_s_sleep(5);          // ~320 cycles, issued once
    }

    const int plane = bid >> 2;               // 512 planes
    const int strip = bid & 3;
    const int y0    = strip * ROWS;
    const int ch    = plane & 63;

    float s   = fmaxf(sigma[ch], 1e-6f);
    float eg  = __expf(-1.0f / (2.0f * s * s));
    float inv = 1.0f / (1.0f + 2.0f * eg);
    const float w0s = eg * inv, w1s = inv, l = lam[0];
    const float W0Z = -l * w0s * AZS;         // vertical taps, -lam and AZS folded
    const float W1Z = -l * w1s * AZS;
    // edge-lane masked taps: kill the per-stage cndmask on lft/rgt
    const float w0L = (lane == 0)  ? 0.f : w0s;
    const float w0R = (lane == 63) ? 0.f : w0s;

    const float* op_lane = o   + plane * HW + lane * 4;
    float*       up_lane = out + plane * HW + lane * 4;
    const int a_up = ((lane + 63) & 63) << 2;
    const int a_dn = ((lane + 1)  & 63) << 2;

    // per-stage h carries: rows (r-1, r) of conv'd t_{k-1}, in registers
    float hA[DEPTH][4], hB[DEPTH][4];
#pragma unroll
    for (int k = 0; k < DEPTH; ++k)
#pragma unroll
        for (int i = 0; i < 4; ++i) { hA[k][i] = 0.f; hB[k][i] = 0.f; }

    // prologue: prefetch first step's stage-0 rows (y0-10..y0-7, clamped;
    // OOB rows are zeroed by the border steps' rv select before use)
    float pnext[RB][4];
#pragma unroll
    for (int m = 0; m < RB; ++m) {
        int r = y0 - DEPTH + m;
        r = r < 0 ? 0 : (r > 255 ? 255 : r);
        f4 v = *reinterpret_cast<const f4*>(op_lane + r * Ww);
        pnext[m][0] = v.x; pnext[m][1] = v.y; pnext[m][2] = v.z; pnext[m][3] = v.w;
    }

    // border-step bounds: steps touching rows <0 (strip 0) or >255 (strip 3)
    int jb0 = (20 - y0 + 3) / 4; if (jb0 < 0) jb0 = 0;            // first interior
    int jb1 = (262 - y0) / 4 + 1; if (jb1 > NSTEP) jb1 = NSTEP;   // first trailing border

    int j = 0;
#pragma unroll 1
    for (; j < jb0; ++j)  { const int yS = y0 - DEPTH + RB * j; STEP_BODY(true);  }
#pragma unroll 1
    for (; j < jb1; ++j)  { const int yS = y0 - DEPTH + RB * j; STEP_BODY(false); }
#pragma unroll 1
    for (; j < NSTEP; ++j){ const int yS = y0 - DEPTH + RB * j; STEP_BODY(true);  }
}

extern "C" void kernel_launch(void* const* d_in, const int* in_sizes, int n_in,
                              void* d_out, int out_size, void* d_ws, size_t ws_size,
                              hipStream_t stream) {
    (void)in_sizes; (void)n_in; (void)out_size; (void)d_ws; (void)ws_size;
    const float* o     = (const float*)d_in[0];
    const float* sigma = (const float*)d_in[1];
    const float* lam   = (const float*)d_in[2];
    float* out = (float*)d_out;

    k_fused<<<PLANES * STRIPS, 64, 0, stream>>>(o, sigma, lam, out);
}

// Round 18
// 141.592 us; speedup vs baseline: 1.0659x; 1.0659x over previous
//
#include <hip/hip_runtime.h>

typedef float f4 __attribute__((ext_vector_type(4)));

static constexpr int Hh = 256, Ww = 256, HW = Hh * Ww;
static constexpr int PLANES = 512;            // N*C
static constexpr int STRIPS = 4;
static constexpr int ROWS   = Hh / STRIPS;    // 64
static constexpr int DEPTH  = 10;
static constexpr int RB     = 4;              // rows advanced per sweep step
static constexpr int NSTEP  = (ROWS + 2 * DEPTH) / RB;   // 21

#if __has_builtin(__builtin_amdgcn_exp2f)
#define EXP2F(x) __builtin_amdgcn_exp2f(x)
#else
#define EXP2F(x) __expf((x) * 0.6931471805599453f)
#endif

// full-wave lane shifts via DPP (gfx9 lineage: WAVE_SHR1=0x138, WAVE_SHL1=0x130)
// update_dpp(old=0,...) -> out-of-range lanes (lane0 for shr, lane63 for shl)
// read 0, which IS the conv's x-edge zero padding. VALU-rate, no DS pipe.
__device__ __forceinline__ float shr1_f(float x) {   // lane i <- lane i-1
    return __int_as_float(__builtin_amdgcn_update_dpp(
        0, __float_as_int(x), 0x138, 0xf, 0xf, false));
}
__device__ __forceinline__ float shl1_f(float x) {   // lane i <- lane i+1
    return __int_as_float(__builtin_amdgcn_update_dpp(
        0, __float_as_int(x), 0x130, 0xf, 0xf, false));
}

static constexpr float LN2 = 0.6931471805599453f;
static constexpr float L2E = 1.4426950408889634f;
static constexpr float AZS = 10.0f * L2E;     // Z = AZS * z  (BETA+log2e folded)

// deg-2 minimax of ln(1+p), p = 2^(-|Z|); max(Z,0) folded into coefficients
// (error budget: absmax saturated at 2.0 across rounds; threshold 10.04)
static constexpr float A1c = 0.9897f;
static constexpr float A2c = -0.3059f;
static constexpr float TA = -0.12f * LN2;
static constexpr float TB = -0.08f * LN2;
static constexpr float TCA1 = -0.16f * A1c;
static constexpr float TCA2 = -0.16f * A2c;
static constexpr float UA = 0.06f * LN2;
static constexpr float UB = 0.04f * LN2;
static constexpr float UCA1 = 0.08f * A1c;
static constexpr float UCA2 = 0.08f * A2c;

// exp2(-|Z|) folds abs+neg into src modifiers -> ~5 insts
__device__ __forceinline__ float tval_s(float Z) {
    float az = fabsf(Z);
    float p  = EXP2F(-az);
    float r  = fmaf(TCA2, p, TCA1);
    float s  = fmaf(r, p, 1.0f);              // 1 + TC*ln(1+p)
    return fmaf(TA, Z, fmaf(TB, az, s));
}
__device__ __forceinline__ float uval_s(float Z) {
    float az = fabsf(Z);
    float p  = EXP2F(-az);
    float r  = fmaf(UCA2, p, UCA1);
    float su = r * p;                         // UC*ln(1+p)
    return fmaf(UA, Z, fmaf(UB, az, su));
}

// One sweep step. BORDER is a literal; pnext[4][4] carries the next step's
// stage-0 rows (prefetched one full step ahead -> no vmcnt stall at stage 0).
#define STEP_BODY(BORDER) do {                                               \
    float og[DEPTH + RB][4];                                                 \
    /* stage-0 rows: consume prefetch (long since returned), scale to Z */   \
    _Pragma("unroll")                                                        \
    for (int m = 0; m < RB; ++m)                                             \
        { _Pragma("unroll") for (int i = 0; i < 4; ++i) og[DEPTH + m][i] = AZS * pnext[m][i]; } \
    /* issue current-step rows og[9]..og[0] in consumption order (raw) */    \
    _Pragma("unroll")                                                        \
    for (int t = DEPTH - 1; t >= 0; --t) {                                   \
        int r = yS - DEPTH + t;                                              \
        if (BORDER) r = r < 0 ? 0 : (r > 255 ? 255 : r);                     \
        f4 v = *reinterpret_cast<const f4*>(op_lane + r * Ww);               \
        og[t][0] = v.x; og[t][1] = v.y; og[t][2] = v.z; og[t][3] = v.w;      \
    }                                                                        \
    /* issue NEXT step's stage-0 prefetch (rows yS+4..yS+7, always clamped) */\
    _Pragma("unroll")                                                        \
    for (int m = 0; m < RB; ++m) {                                           \
        int r = yS + RB + m;                                                 \
        r = r < 0 ? 0 : (r > 255 ? 255 : r);                                 \
        f4 v = *reinterpret_cast<const f4*>(op_lane + r * Ww);               \
        pnext[m][0] = v.x; pnext[m][1] = v.y; pnext[m][2] = v.z; pnext[m][3] = v.w; \
    }                                                                        \
    asm volatile("" ::: "memory");               /* pin loads above compute */\
    float tin[RB][4];                                                        \
    _Pragma("unroll")                                                        \
    for (int m = 0; m < RB; ++m) {                                           \
        const bool rv = !BORDER || (unsigned)(yS + m) < 256u;                \
        _Pragma("unroll")                                                    \
        for (int i = 0; i < 4; ++i) {                                        \
            float tv = tval_s(og[DEPTH + m][i]);                             \
            tin[m][i] = rv ? tv : 0.f;                                       \
        }                                                                    \
    }                                                                        \
    /* scale current rows to Z-domain (loads now have ~stage-0 of cover) */  \
    _Pragma("unroll")                                                        \
    for (int t = 0; t < DEPTH; ++t)                                          \
        { _Pragma("unroll") for (int i = 0; i < 4; ++i) og[t][i] *= AZS; }   \
    _Pragma("unroll")                                                        \
    for (int k = 1; k <= DEPTH; ++k) {                                       \
        float hn[RB][4];                                                     \
        _Pragma("unroll")                                                    \
        for (int m = 0; m < RB; ++m) {                                       \
            float lft = shr1_f(tin[m][3]);   /* lane i-1's t[3]; lane0 -> 0 */\
            float rgt = shl1_f(tin[m][0]);   /* lane i+1's t[0]; lane63 -> 0 */\
            hn[m][0] = fmaf(w1s, tin[m][0], fmaf(w0s, tin[m][1], w0s * lft)); \
            hn[m][1] = fmaf(w1s, tin[m][1], w0s * (tin[m][0] + tin[m][2]));  \
            hn[m][2] = fmaf(w1s, tin[m][2], w0s * (tin[m][1] + tin[m][3]));  \
            hn[m][3] = fmaf(w1s, tin[m][3], fmaf(w0s, tin[m][2], w0s * rgt)); \
        }                                                                    \
        _Pragma("unroll")                                                    \
        for (int m = 0; m < RB; ++m) {                                       \
            const bool rv = !BORDER || (unsigned)(yS - k + m) < 256u;        \
            _Pragma("unroll")                                                \
            for (int i = 0; i < 4; ++i) {                                    \
                float h_im1 = (m == 0) ? hA[k - 1][i] : (m == 1) ? hB[k - 1][i] : hn[m - 2][i]; \
                float h_i   = (m == 0) ? hB[k - 1][i] : hn[m - 1][i];        \
                float Z = fmaf(W0Z, h_im1 + hn[m][i],                        \
                          fmaf(W1Z, h_i, og[DEPTH - k + m][i]));             \
                if (k < DEPTH) { float tv = tval_s(Z); tin[m][i] = rv ? tv : 0.f; } \
                else           { tin[m][i] = uval_s(Z); }                    \
            }                                                                \
        }                                                                    \
        _Pragma("unroll")                                                    \
        for (int i = 0; i < 4; ++i) { hA[k - 1][i] = hn[2][i]; hB[k - 1][i] = hn[3][i]; } \
    }                                                                        \
    _Pragma("unroll")                                                        \
    for (int m = 0; m < RB; ++m) {                                           \
        const int r = yS - DEPTH + m;                                        \
        if (r >= y0 && r < y0 + ROWS) {                                      \
            f4 v; v.x = tin[m][0]; v.y = tin[m][1]; v.z = tin[m][2]; v.w = tin[m][3]; \
            *reinterpret_cast<f4*>(up_lane + r * Ww) = v;                    \
        }                                                                    \
    }                                                                        \
} while (0)

// R16 config (2048 waves = 2/SIMD, VGPR~100, zero scratch, de-phase sleep)
// + ONE change: ds_bpermute -> DPP wave shifts. The DS pipe is now entirely
// out of the kernel: no LDS ops, no lgkmcnt waits, no a_up/a_dn, and the
// DPP bound-ctrl zero-fill provides the x-edge padding (w0L/w0R dropped).
__global__ __launch_bounds__(64)
__attribute__((amdgpu_waves_per_eu(2, 2)))
void k_fused(const float* __restrict__ o, const float* __restrict__ sigma,
             const float* __restrict__ lam, float* __restrict__ out) {
    const int lane  = threadIdx.x;
    const int bid   = blockIdx.x;

    if (bid >= (PLANES * STRIPS) / 2) {
        __builtin_amdgcn_s_sleep(5);          // de-phase the 2nd resident wave
    }

    const int plane = bid >> 2;               // 512 planes
    const int strip = bid & 3;
    const int y0    = strip * ROWS;
    const int ch    = plane & 63;

    float s   = fmaxf(sigma[ch], 1e-6f);
    float eg  = __expf(-1.0f / (2.0f * s * s));
    float inv = 1.0f / (1.0f + 2.0f * eg);
    const float w0s = eg * inv, w1s = inv, l = lam[0];
    const float W0Z = -l * w0s * AZS;         // vertical taps, -lam and AZS folded
    const float W1Z = -l * w1s * AZS;

    const float* op_lane = o   + plane * HW + lane * 4;
    float*       up_lane = out + plane * HW + lane * 4;

    // per-stage h carries: rows (r-1, r) of conv'd t_{k-1}, in registers
    float hA[DEPTH][4], hB[DEPTH][4];
#pragma unroll
    for (int k = 0; k < DEPTH; ++k)
#pragma unroll
        for (int i = 0; i < 4; ++i) { hA[k][i] = 0.f; hB[k][i] = 0.f; }

    // prologue: prefetch first step's stage-0 rows (y0-10..y0-7, clamped;
    // OOB rows are zeroed by the border steps' rv select before use)
    float pnext[RB][4];
#pragma unroll
    for (int m = 0; m < RB; ++m) {
        int r = y0 - DEPTH + m;
        r = r < 0 ? 0 : (r > 255 ? 255 : r);
        f4 v = *reinterpret_cast<const f4*>(op_lane + r * Ww);
        pnext[m][0] = v.x; pnext[m][1] = v.y; pnext[m][2] = v.z; pnext[m][3] = v.w;
    }

    // border-step bounds: steps touching rows <0 (strip 0) or >255 (strip 3)
    int jb0 = (20 - y0 + 3) / 4; if (jb0 < 0) jb0 = 0;            // first interior
    int jb1 = (262 - y0) / 4 + 1; if (jb1 > NSTEP) jb1 = NSTEP;   // first trailing border

    int j = 0;
#pragma unroll 1
    for (; j < jb0; ++j)  { const int yS = y0 - DEPTH + RB * j; STEP_BODY(true);  }
#pragma unroll 1
    for (; j < jb1; ++j)  { const int yS = y0 - DEPTH + RB * j; STEP_BODY(false); }
#pragma unroll 1
    for (; j < NSTEP; ++j){ const int yS = y0 - DEPTH + RB * j; STEP_BODY(true);  }
}

extern "C" void kernel_launch(void* const* d_in, const int* in_sizes, int n_in,
                              void* d_out, int out_size, void* d_ws, size_t ws_size,
                              hipStream_t stream) {
    (void)in_sizes; (void)n_in; (void)out_size; (void)d_ws; (void)ws_size;
    const float* o     = (const float*)d_in[0];
    const float* sigma = (const float*)d_in[1];
    const float* lam   = (const float*)d_in[2];
    float* out = (float*)d_out;

    k_fused<<<PLANES * STRIPS, 64, 0, stream>>>(o, sigma, lam, out);
}

// Round 19
// 136.618 us; speedup vs baseline: 1.1047x; 1.0364x over previous
//
#include <hip/hip_runtime.h>

typedef float f4 __attribute__((ext_vector_type(4)));

static constexpr int Hh = 256, Ww = 256, HW = Hh * Ww;
static constexpr int PLANES = 512;            // N*C
static constexpr int STRIPS = 4;
static constexpr int ROWS   = Hh / STRIPS;    // 64
static constexpr int DEPTH  = 10;
static constexpr int RB     = 4;              // rows advanced per sweep step
static constexpr int NSTEP  = (ROWS + 2 * DEPTH) / RB;   // 21
static constexpr int WROWS  = DEPTH + RB;     // 14-row sliding window

#if __has_builtin(__builtin_amdgcn_exp2f)
#define EXP2F(x) __builtin_amdgcn_exp2f(x)
#else
#define EXP2F(x) __expf((x) * 0.6931471805599453f)
#endif

// full-wave lane shifts via DPP (WAVE_SHR1=0x138, WAVE_SHL1=0x130); old=0 ->
// boundary lanes read 0 == the conv's x-edge zero padding. VALU-rate, no DS.
__device__ __forceinline__ float shr1_f(float x) {   // lane i <- lane i-1
    return __int_as_float(__builtin_amdgcn_update_dpp(
        0, __float_as_int(x), 0x138, 0xf, 0xf, false));
}
__device__ __forceinline__ float shl1_f(float x) {   // lane i <- lane i+1
    return __int_as_float(__builtin_amdgcn_update_dpp(
        0, __float_as_int(x), 0x130, 0xf, 0xf, false));
}

static constexpr float LN2 = 0.6931471805599453f;
static constexpr float L2E = 1.4426950408889634f;
static constexpr float AZS = 10.0f * L2E;     // Z = AZS * z  (BETA+log2e folded)

// deg-2 minimax of ln(1+p), p = 2^(-|Z|); max(Z,0) folded into coefficients
// (error budget: absmax saturated at 2.0 across rounds; threshold 10.04)
static constexpr float A1c = 0.9897f;
static constexpr float A2c = -0.3059f;
static constexpr float TA = -0.12f * LN2;
static constexpr float TB = -0.08f * LN2;
static constexpr float TCA1 = -0.16f * A1c;
static constexpr float TCA2 = -0.16f * A2c;
static constexpr float UA = 0.06f * LN2;
static constexpr float UB = 0.04f * LN2;
static constexpr float UCA1 = 0.08f * A1c;
static constexpr float UCA2 = 0.08f * A2c;

__device__ __forceinline__ float tval_s(float Z) {
    float az = fabsf(Z);
    float p  = EXP2F(-az);                    // abs+neg fold into src modifiers
    float r  = fmaf(TCA2, p, TCA1);
    float s  = fmaf(r, p, 1.0f);              // 1 + TC*ln(1+p)
    return fmaf(TA, Z, fmaf(TB, az, s));
}
__device__ __forceinline__ float uval_s(float Z) {
    float az = fabsf(Z);
    float p  = EXP2F(-az);
    float r  = fmaf(UCA2, p, UCA1);
    float su = r * p;                         // UC*ln(1+p)
    return fmaf(UA, Z, fmaf(UB, az, su));
}

// One sweep step. obuf[14][4] is a persistent double-buffer holding the
// WHOLE 14-row o-window, loaded one full step (~8K cyc) ahead -> zero vmcnt
// exposure anywhere in the step (R18 residual-idle theory). BORDER only
// affects the eval-time rv masks; loads are always clamped (garbage rows
// are masked before any valid use).
#define STEP_BODY(BORDER) do {                                               \
    /* 1. consume prefetch: scale raw rows to Z-domain (og = AZS*obuf) */    \
    float og[WROWS][4];                                                      \
    _Pragma("unroll")                                                        \
    for (int t = 0; t < WROWS; ++t)                                          \
        { _Pragma("unroll") for (int i = 0; i < 4; ++i) og[t][i] = AZS * obuf[t][i]; } \
    /* 2. issue next step's full window (rows yS-6 .. yS+7, clamped) */      \
    _Pragma("unroll")                                                        \
    for (int t = 0; t < WROWS; ++t) {                                        \
        int r = yS + RB - DEPTH + t;                                         \
        r = r < 0 ? 0 : (r > 255 ? 255 : r);                                 \
        f4 v = *reinterpret_cast<const f4*>(op_lane + r * Ww);               \
        obuf[t][0] = v.x; obuf[t][1] = v.y; obuf[t][2] = v.z; obuf[t][3] = v.w; \
    }                                                                        \
    asm volatile("" ::: "memory");               /* pin loads above compute */\
    /* 3. stage 0: t0 rows yS..yS+3 (og slots 10..13) */                     \
    float tin[RB][4];                                                        \
    _Pragma("unroll")                                                        \
    for (int m = 0; m < RB; ++m) {                                           \
        const bool rv = !BORDER || (unsigned)(yS + m) < 256u;                \
        _Pragma("unroll")                                                    \
        for (int i = 0; i < 4; ++i) {                                        \
            float tv = tval_s(og[DEPTH + m][i]);                             \
            tin[m][i] = rv ? tv : 0.f;                                       \
        }                                                                    \
    }                                                                        \
    /* 4. stages 1..10 */                                                    \
    _Pragma("unroll")                                                        \
    for (int k = 1; k <= DEPTH; ++k) {                                       \
        float hn[RB][4];                                                     \
        _Pragma("unroll")                                                    \
        for (int m = 0; m < RB; ++m) {                                       \
            float lft = shr1_f(tin[m][3]);   /* lane i-1's t[3]; lane0 -> 0 */\
            float rgt = shl1_f(tin[m][0]);   /* lane i+1's t[0]; lane63 -> 0 */\
            hn[m][0] = fmaf(w1s, tin[m][0], fmaf(w0s, tin[m][1], w0s * lft)); \
            hn[m][1] = fmaf(w1s, tin[m][1], w0s * (tin[m][0] + tin[m][2]));  \
            hn[m][2] = fmaf(w1s, tin[m][2], w0s * (tin[m][1] + tin[m][3]));  \
            hn[m][3] = fmaf(w1s, tin[m][3], fmaf(w0s, tin[m][2], w0s * rgt)); \
        }                                                                    \
        _Pragma("unroll")                                                    \
        for (int m = 0; m < RB; ++m) {                                       \
            const bool rv = !BORDER || (unsigned)(yS - k + m) < 256u;        \
            _Pragma("unroll")                                                \
            for (int i = 0; i < 4; ++i) {                                    \
                float h_im1 = (m == 0) ? hA[k - 1][i] : (m == 1) ? hB[k - 1][i] : hn[m - 2][i]; \
                float h_i   = (m == 0) ? hB[k - 1][i] : hn[m - 1][i];        \
                float Z = fmaf(W0Z, h_im1 + hn[m][i],                        \
                          fmaf(W1Z, h_i, og[DEPTH - k + m][i]));             \
                if (k < DEPTH) { float tv = tval_s(Z); tin[m][i] = rv ? tv : 0.f; } \
                else           { tin[m][i] = uval_s(Z); }                    \
            }                                                                \
        }                                                                    \
        _Pragma("unroll")                                                    \
        for (int i = 0; i < 4; ++i) { hA[k - 1][i] = hn[2][i]; hB[k - 1][i] = hn[3][i]; } \
    }                                                                        \
    /* 5. store u rows r = yS-10+m inside this strip */                      \
    _Pragma("unroll")                                                        \
    for (int m = 0; m < RB; ++m) {                                           \
        const int r = yS - DEPTH + m;                                        \
        if (r >= y0 && r < y0 + ROWS) {                                      \
            f4 v; v.x = tin[m][0]; v.y = tin[m][1]; v.z = tin[m][2]; v.w = tin[m][3]; \
            *reinterpret_cast<f4*>(up_lane + r * Ww) = v;                    \
        }                                                                    \
    }                                                                        \
} while (0)

// R18 config (2048 waves = 2/SIMD, DPP hconv, de-phase sleep, zero scratch)
// + ONE change: full-window o double-buffer (obuf) so every global load has
// a full step of latency cover. VGPR rises ~100 -> ~200-240; 2-wave budget
// is 256 so no spill expected (guard: WRITE_SIZE == 131072 KB exactly).
__global__ __launch_bounds__(64)
__attribute__((amdgpu_waves_per_eu(2, 2)))
void k_fused(const float* __restrict__ o, const float* __restrict__ sigma,
             const float* __restrict__ lam, float* __restrict__ out) {
    const int lane  = threadIdx.x;
    const int bid   = blockIdx.x;

    if (bid >= (PLANES * STRIPS) / 2) {
        __builtin_amdgcn_s_sleep(5);          // de-phase the 2nd resident wave
    }

    const int plane = bid >> 2;               // 512 planes
    const int strip = bid & 3;
    const int y0    = strip * ROWS;
    const int ch    = plane & 63;

    float s   = fmaxf(sigma[ch], 1e-6f);
    float eg  = __expf(-1.0f / (2.0f * s * s));
    float inv = 1.0f / (1.0f + 2.0f * eg);
    const float w0s = eg * inv, w1s = inv, l = lam[0];
    const float W0Z = -l * w0s * AZS;         // vertical taps, -lam and AZS folded
    const float W1Z = -l * w1s * AZS;

    const float* op_lane = o   + plane * HW + lane * 4;
    float*       up_lane = out + plane * HW + lane * 4;

    // per-stage h carries: rows (r-1, r) of conv'd t_{k-1}, in registers
    float hA[DEPTH][4], hB[DEPTH][4];
#pragma unroll
    for (int k = 0; k < DEPTH; ++k)
#pragma unroll
        for (int i = 0; i < 4; ++i) { hA[k][i] = 0.f; hB[k][i] = 0.f; }

    // prologue: load step 0's full window (rows y0-20 .. y0-7, clamped;
    // OOB rows are garbage masked by the border steps' rv selects)
    float obuf[WROWS][4];
#pragma unroll
    for (int t = 0; t < WROWS; ++t) {
        int r = y0 - 2 * DEPTH + t;
        r = r < 0 ? 0 : (r > 255 ? 255 : r);
        f4 v = *reinterpret_cast<const f4*>(op_lane + r * Ww);
        obuf[t][0] = v.x; obuf[t][1] = v.y; obuf[t][2] = v.z; obuf[t][3] = v.w;
    }

    // border-step bounds: steps touching rows <0 (strip 0) or >255 (strip 3)
    int jb0 = (20 - y0 + 3) / 4; if (jb0 < 0) jb0 = 0;            // first interior
    int jb1 = (262 - y0) / 4 + 1; if (jb1 > NSTEP) jb1 = NSTEP;   // first trailing border

    int j = 0;
#pragma unroll 1
    for (; j < jb0; ++j)  { const int yS = y0 - DEPTH + RB * j; STEP_BODY(true);  }
#pragma unroll 1
    for (; j < jb1; ++j)  { const int yS = y0 - DEPTH + RB * j; STEP_BODY(false); }
#pragma unroll 1
    for (; j < NSTEP; ++j){ const int yS = y0 - DEPTH + RB * j; STEP_BODY(true);  }
}

extern "C" void kernel_launch(void* const* d_in, const int* in_sizes, int n_in,
                              void* d_out, int out_size, void* d_ws, size_t ws_size,
                              hipStream_t stream) {
    (void)in_sizes; (void)n_in; (void)out_size; (void)d_ws; (void)ws_size;
    const float* o     = (const float*)d_in[0];
    const float* sigma = (const float*)d_in[1];
    const float* lam   = (const float*)d_in[2];
    float* out = (float*)d_out;

    k_fused<<<PLANES * STRIPS, 64, 0, stream>>>(o, sigma, lam, out);
}